// Round 9
// baseline (5775.061 us; speedup 1.0000x reference)
//
#include <hip/hip_runtime.h>

// Problem constants
#define BB 32      // batch
#define SS 512     // seq len
#define II 512     // input size
#define HH 512     // hidden
#define GG 2048    // 4*H

typedef unsigned short u16;
typedef unsigned int   u32;
typedef unsigned long long u64;

typedef __attribute__((ext_vector_type(8))) short bf16x8;
typedef __attribute__((ext_vector_type(4))) float f32x4;

__device__ __forceinline__ float b2f(u16 h) {
    return __uint_as_float(((u32)h) << 16);
}
__device__ __forceinline__ u16 f2b(float f) {  // RNE f32 -> bf16
    u32 u = __float_as_uint(f);
    u32 r = (u + 0x7FFFu + ((u >> 16) & 1u)) >> 16;
    return (u16)r;
}

// ---- global_load_lds helper (16B per lane, uniform LDS base + lane*16) ----
#ifndef __has_builtin
#define __has_builtin(x) 0
#endif
#if __has_builtin(__builtin_amdgcn_global_load_lds)
#define HAVE_GLL 1
#else
#define HAVE_GLL 0
#endif

typedef __attribute__((address_space(1))) void as1_void;
typedef __attribute__((address_space(3))) void as3_void;

__device__ __forceinline__ void gload16(const void* g, void* l, int lane) {
#if HAVE_GLL
    __builtin_amdgcn_global_load_lds((as1_void*)g, (as3_void*)l, 16, 0, 0);
#else
    *(bf16x8*)((char*)l + lane * 16) = *(const bf16x8*)g;
#endif
}

// ---------------- convert x: [B][S][I] f32 -> [S][B][I] bf16 ----------------
__global__ void k_convert_x(const float* __restrict__ x, u16* __restrict__ xbf) {
    const int n4 = BB * SS * II / 4;  // 2,097,152
    for (int e4 = blockIdx.x * blockDim.x + threadIdx.x; e4 < n4;
         e4 += gridDim.x * blockDim.x) {
        int e = e4 * 4;
        int s = e >> 14;         // / (B*I = 16384)
        int b = (e >> 9) & 31;
        int i = e & 511;
        float4 v = *(const float4*)(x + (size_t)b * (SS * II) + (size_t)s * II + i);
        ushort4 o;
        o.x = f2b(v.x); o.y = f2b(v.y); o.z = f2b(v.z); o.w = f2b(v.w);
        *(ushort4*)(xbf + (size_t)s * (BB * II) + (size_t)b * II + i) = o;
    }
}

// ---------------- generic f32 -> bf16 cast ----------------
__global__ void k_cast(const float* __restrict__ src, u16* __restrict__ dst, int n4) {
    for (int e4 = blockIdx.x * blockDim.x + threadIdx.x; e4 < n4;
         e4 += gridDim.x * blockDim.x) {
        float4 v = *(const float4*)(src + (size_t)e4 * 4);
        ushort4 o;
        o.x = f2b(v.x); o.y = f2b(v.y); o.z = f2b(v.z); o.w = f2b(v.w);
        *(ushort4*)(dst + (size_t)e4 * 4) = o;
    }
}

// ---------------- input projection GEMM (128x128 tile, BK=64, MFMA bf16) ----
#define BKP 64

__launch_bounds__(256)
__global__ void k_proj(const u16* __restrict__ A,
                       const u16* __restrict__ Wf_, const u16* __restrict__ Wb_,
                       const float* __restrict__ bihf, const float* __restrict__ bhhf,
                       const float* __restrict__ bihb, const float* __restrict__ bhhb,
                       u16* __restrict__ xpf, u16* __restrict__ xpb,
                       int K) {
    const int dir = blockIdx.z;
    const u16* Wm = dir ? Wb_ : Wf_;
    const float* bih = dir ? bihb : bihf;
    const float* bhh = dir ? bhhb : bhhf;
    u16* xp = dir ? xpb : xpf;

    __shared__ __align__(16) u16 As[128 * BKP];
    __shared__ __align__(16) u16 Bs[128 * BKP];

    const int t    = threadIdx.x;
    const int lane = t & 63;
    const int w    = t >> 6;
    const int wm   = w >> 1, wn = w & 1;
    const int m0   = blockIdx.x * 128;
    const int n0   = blockIdx.y * 128;

    f32x4 acc[4][4] = {};

    for (int kt = 0; kt < K; kt += BKP) {
        #pragma unroll
        for (int i = 0; i < 4; ++i) {
            int c   = (w * 4 + i) * 64 + lane;   // physical chunk 0..1023
            int row = c >> 3;
            int lc  = (c & 7) ^ (row & 7);       // logical chunk within row
            int gk  = kt + lc * 8;
            gload16(A  + (size_t)(m0 + row) * K + gk, (char*)As + (w * 4 + i) * 1024, lane);
            gload16(Wm + (size_t)(n0 + row) * K + gk, (char*)Bs + (w * 4 + i) * 1024, lane);
        }
        __syncthreads();

        #pragma unroll
        for (int ks = 0; ks < 2; ++ks) {
            const int kc = ks * 4 + (lane >> 4);
            bf16x8 af[4], bfr[4];
            #pragma unroll
            for (int mi = 0; mi < 4; ++mi) {
                int row = wm * 64 + mi * 16 + (lane & 15);
                af[mi] = *(const bf16x8*)&As[row * BKP + ((kc ^ (row & 7)) << 3)];
            }
            #pragma unroll
            for (int ni = 0; ni < 4; ++ni) {
                int row = wn * 64 + ni * 16 + (lane & 15);
                bfr[ni] = *(const bf16x8*)&Bs[row * BKP + ((kc ^ (row & 7)) << 3)];
            }
            #pragma unroll
            for (int mi = 0; mi < 4; ++mi)
                #pragma unroll
                for (int ni = 0; ni < 4; ++ni)
                    acc[mi][ni] = __builtin_amdgcn_mfma_f32_16x16x32_bf16(
                        af[mi], bfr[ni], acc[mi][ni], 0, 0, 0);
        }
        __syncthreads();
    }

    #pragma unroll
    for (int ni = 0; ni < 4; ++ni) {
        int n = n0 + wn * 64 + ni * 16 + (lane & 15);
        float bias = bih[n] + bhh[n];
        #pragma unroll
        for (int mi = 0; mi < 4; ++mi) {
            #pragma unroll
            for (int r = 0; r < 4; ++r) {
                int m = m0 + wm * 64 + mi * 16 + (lane >> 4) * 4 + r;
                xp[(size_t)m * GG + n] = f2b(acc[mi][ni][r] + bias);
            }
        }
    }
}

// ---------------- persistent recurrence kernel (stamped, wave-autonomous) --
// grid = 64 WGs x 512 thr (8 waves). dir = bid>>5, wg = bid&31 owns 16 h-cols.
// Wave (cg = wv&3, m = wv>>2): ALL 4 gates for cols j0+cg*4..+3, batch
// m*16..+15. B-operand packed with MIXED rows: B-row r -> gate r>>2, col
// cg*4+(r&3). Gate-combine is intra-wave (LDS scratch + lgkmcnt, no barrier);
// each wave publishes right after its own 16 MFMAs. ONE barrier per step
// (hl stage -> MFMA). Safety: stage(s+1) is poll-gated (all WGs published
// s+1 => every wave finished epilogue(s)); xq double-buffered.
__launch_bounds__(512, 1)
__global__ void k_rec(const u16* __restrict__ xpf, const u16* __restrict__ xpb,
                      const float* __restrict__ whf, const float* __restrict__ whb,
                      u64* __restrict__ Hd,          // [2 par][2 dir][32][256] u64
                      u16* __restrict__ hs0,         // layer0 out [s][b][1024] bf16
                      float* __restrict__ out,       // layer1 out [b][s][1024] f32
                      float* __restrict__ fin,       // final h (65536 f32) then c
                      int layer) {
    const int bid  = blockIdx.x;
    const int dir  = bid >> 5;
    const int wg   = bid & 31;
    const int j0   = wg * 16;
    const u16*  xp = dir ? xpb : xpf;
    const float* W = dir ? whb : whf;

    const int t    = threadIdx.x;
    const int lane = t & 63;
    const int wv   = t >> 6;           // wave 0..7
    const int cg   = wv & 3;           // column group (4 cols)
    const int m    = wv >> 2;          // batch half

    __shared__ __align__(16) u16 Wfr[4][16][512];   // [cg][kt][lane*8] 64 KB
    __shared__ __align__(16) u16 hl[32 * 512];      // h tile, swizzled, 32 KB
    __shared__ float xq[2][32 * 68];                // xp slice f32, dbuf, 17.4 KB
    __shared__ float scr[8][320];                   // per-wave gate scratch 10 KB

    // ---- pack W_hh into MIXED-row fragment order (once) ----
    for (int it = 0; it < 8; ++it) {
        int task = it * 512 + t;           // 0..4095
        int l    = task & 63;
        int blk  = task >> 6;              // 0..63 = pcg*16 + kt
        int pcg  = blk >> 4;
        int kt   = blk & 15;
        int r    = l & 15;                 // mixed row: gate r>>2, col r&3
        int grow = (r >> 2) * 512 + j0 + pcg * 4 + (r & 3);
        const float* src = W + (size_t)grow * 512 + kt * 32 + (l >> 4) * 8;
        float4 v0 = *(const float4*)src;
        float4 v1 = *(const float4*)(src + 4);
        union { bf16x8 v; u16 a[8]; } u;
        u.a[0] = f2b(v0.x); u.a[1] = f2b(v0.y); u.a[2] = f2b(v0.z); u.a[3] = f2b(v0.w);
        u.a[4] = f2b(v1.x); u.a[5] = f2b(v1.y); u.a[6] = f2b(v1.z); u.a[7] = f2b(v1.w);
        *(bf16x8*)&Wfr[pcg][kt][l * 8] = u.v;
    }
    __syncthreads();

    // poll/stage mapping: thread covers rows r0..r0+15, u32-word wd
    const int wd     = t & 255;
    const int r0     = (t >> 8) * 16;
    const int sc_c   = wd >> 2;            // logical 16B chunk within row
    const int sc_sub = (wd & 3) * 4;       // byte within chunk

    // epilogue mapping: lane -> (batch eb, col ecol); one (b,col) per lane
    const int bl   = lane >> 2;            // 0..15
    const int cc   = lane & 3;             // 0..3
    const int eb   = m * 16 + bl;
    const int ecol = j0 + cg * 4 + cc;
    float creg = 0.f;

    for (int s = 0; s < SS; ++s) {
        const int sa = dir ? (SS - 1 - s) : s;

        // ---- A: issue poll loads FIRST (their latency is the wait) ----
        u64 w[16];
        const u64* Hrd = Hd + ((size_t)((s & 1) * 2 + dir)) * (32 * 256);
        const u32 tgt = (u32)((layer << 10) | s);
        if (s > 0) {
            #pragma unroll
            for (int i = 0; i < 16; ++i)
                w[i] = __hip_atomic_load(Hrd + (r0 + i) * 256 + wd,
                                         __ATOMIC_RELAXED, __HIP_MEMORY_SCOPE_AGENT);
        }

        // ---- B: stage xp slice into xq[s&1] (fills the poll RT window) ----
        {
            int b = t >> 4, seg = t & 15;      // g = seg>>2, j4 = (seg&3)*4
            int g = seg >> 2, j4 = (seg & 3) * 4;
            const u16* xsrc = xp + (size_t)(sa * 32 + b) * GG + g * 512 + j0 + j4;
            ushort4 v = *(const ushort4*)xsrc;
            float* xd = &xq[s & 1][b * 68 + g * 16 + j4];
            xd[0] = b2f(v.x); xd[1] = b2f(v.y); xd[2] = b2f(v.z); xd[3] = b2f(v.w);
        }

        // ---- C: check + batched full retry (r5-proven), then stage hl ----
        if (s > 0) {
            for (;;) {
                bool ok = true;
                #pragma unroll
                for (int i = 0; i < 16; ++i) {
                    ok = ok && (((u32)w[i] & 0xffffu) == tgt)
                            && ((((u32)(w[i] >> 32)) & 0xffffu) == tgt);
                }
                if (__all(ok)) break;
                #pragma unroll
                for (int i = 0; i < 16; ++i)
                    w[i] = __hip_atomic_load(Hrd + (r0 + i) * 256 + wd,
                                             __ATOMIC_RELAXED, __HIP_MEMORY_SCOPE_AGENT);
            }
            #pragma unroll
            for (int i = 0; i < 16; ++i) {
                int r = r0 + i;
                u32 two = (u32)((w[i] >> 16) & 0xffffu) | ((u32)(w[i] >> 48) << 16);
                int off = r * 1024 + ((sc_c ^ (r & 7)) << 4) + sc_sub;
                *(u32*)((char*)hl + off) = two;
            }
        } else {
            #pragma unroll
            for (int i = 0; i < 16; ++i) {
                int r = r0 + i;
                int off = r * 1024 + ((sc_c ^ (r & 7)) << 4) + sc_sub;
                *(u32*)((char*)hl + off) = 0u;
            }
        }
        __syncthreads();   // the ONLY per-step barrier (stage -> MFMA)

        // ---- D: MFMA: 16 kt, A = batch rows m*16..+15, B = mixed rows ----
        f32x4 acc = {0.f, 0.f, 0.f, 0.f};
        {
            const int b0 = lane & 15, q = lane >> 4;
            #pragma unroll
            for (int kt = 0; kt < 16; ++kt) {
                int pc = ((kt << 2) + q) ^ (b0 & 7);
                bf16x8 a0 = *(const bf16x8*)&hl[(b0 + m * 16) * 512 + pc * 8];
                bf16x8 Bv = *(const bf16x8*)&Wfr[cg][kt][lane * 8];
                acc = __builtin_amdgcn_mfma_f32_16x16x32_bf16(a0, Bv, acc, 0, 0, 0);
            }
            // intra-wave gate gather: acc[reg] = (gate r>>2, col r&3,
            // batch q*4+reg) with r = lane&15. scr idx = blw*20 + cc*4 + g.
            const int r = lane & 15;
            #pragma unroll
            for (int reg = 0; reg < 4; ++reg)
                scr[wv][(q * 4 + reg) * 20 + (r & 3) * 4 + (r >> 2)] = acc[reg];
        }
        asm volatile("s_waitcnt lgkmcnt(0)" ::: "memory");
        __builtin_amdgcn_sched_barrier(0);   // keep reads below the wait (rule #18)

        // ---- E: per-wave epilogue: one (b,col) per lane ----
        {
            const float* xrow = &xq[s & 1][eb * 68];
            float gi = scr[wv][bl * 20 + cc * 4 + 0] + xrow[0 * 16 + cg * 4 + cc];
            float gf = scr[wv][bl * 20 + cc * 4 + 1] + xrow[1 * 16 + cg * 4 + cc];
            float gg = scr[wv][bl * 20 + cc * 4 + 2] + xrow[2 * 16 + cg * 4 + cc];
            float go = scr[wv][bl * 20 + cc * 4 + 3] + xrow[3 * 16 + cg * 4 + cc];
            float ig = 1.f / (1.f + __expf(-gi));
            float fg = 1.f / (1.f + __expf(-gf));
            float gt = tanhf(gg);
            float og = 1.f / (1.f + __expf(-go));
            float c  = fg * creg + ig * gt;
            float h  = og * tanhf(c);
            creg = c;

            // publish stamped h word IMMEDIATELY (critical path)
            u32* Hwr32 = (u32*)(Hd + ((size_t)(((s + 1) & 1) * 2 + dir)) * (32 * 256));
            const u32 pst = (u32)((layer << 10) | (s + 1));
            __hip_atomic_store(Hwr32 + eb * 512 + ecol,
                               ((u32)f2b(h) << 16) | pst,
                               __ATOMIC_RELAXED, __HIP_MEMORY_SCOPE_AGENT);

            // slow-path outputs (off critical path)
            if (layer == 0) {
                hs0[(size_t)sa * (BB * 1024) + (size_t)eb * 1024 + dir * 512 + ecol]
                    = f2b(h);
            } else {
                out[(size_t)eb * (SS * 1024) + (size_t)sa * 1024 + dir * 512 + ecol] = h;
            }
            if (s == SS - 1) {
                int sl = layer * 2 + dir;
                fin[(size_t)sl * (32 * 512) + eb * 512 + ecol] = h;
                fin[65536 + (size_t)sl * (32 * 512) + eb * 512 + ecol] = c;
            }
        }
        // no second barrier: next iteration's hl/xq writes are poll-gated
    }
}

// ---------------- workspace layout (bytes) ----------------
#define OFF_XBF   ((size_t)0)                       // 16,777,216
#define OFF_HS0   ((size_t)16777216)                // 33,554,432
#define OFF_XPF   ((size_t)50331648)                // 67,108,864
#define OFF_XPB   ((size_t)117440512)               // 67,108,864
#define OFF_WIH0F ((size_t)184549376)               // 2,097,152
#define OFF_WIH0B ((size_t)186646528)               // 2,097,152
#define OFF_WIH1F ((size_t)188743680)               // 4,194,304
#define OFF_WIH1B ((size_t)192937984)               // 4,194,304
#define OFF_HST   ((size_t)197132288)               // 262,144 (stamped h)

extern "C" void kernel_launch(void* const* d_in, const int* in_sizes, int n_in,
                              void* d_out, int out_size, void* d_ws, size_t ws_size,
                              hipStream_t stream) {
    const float* x      = (const float*)d_in[0];
    const float* wih0f  = (const float*)d_in[1];
    const float* whh0f  = (const float*)d_in[2];
    const float* bih0f  = (const float*)d_in[3];
    const float* bhh0f  = (const float*)d_in[4];
    const float* wih0b  = (const float*)d_in[5];
    const float* whh0b  = (const float*)d_in[6];
    const float* bih0b  = (const float*)d_in[7];
    const float* bhh0b  = (const float*)d_in[8];
    const float* wih1f  = (const float*)d_in[9];
    const float* whh1f  = (const float*)d_in[10];
    const float* bih1f  = (const float*)d_in[11];
    const float* bhh1f  = (const float*)d_in[12];
    const float* wih1b  = (const float*)d_in[13];
    const float* whh1b  = (const float*)d_in[14];
    const float* bih1b  = (const float*)d_in[15];
    const float* bhh1b  = (const float*)d_in[16];

    float* out = (float*)d_out;
    char* ws = (char*)d_ws;

    u16* xbf    = (u16*)(ws + OFF_XBF);
    u16* hs0    = (u16*)(ws + OFF_HS0);
    u16* xpf    = (u16*)(ws + OFF_XPF);
    u16* xpb    = (u16*)(ws + OFF_XPB);
    u16* bwih0f = (u16*)(ws + OFF_WIH0F);
    u16* bwih0b = (u16*)(ws + OFF_WIH0B);
    u16* bwih1f = (u16*)(ws + OFF_WIH1F);
    u16* bwih1b = (u16*)(ws + OFF_WIH1B);
    u64* Hd     = (u64*)(ws + OFF_HST);
    float* fin  = out + 16777216;   // final h stack, then c stack at +65536

    // converts
    k_convert_x<<<1024, 256, 0, stream>>>(x, xbf);
    k_cast<<<512, 256, 0, stream>>>(wih0f, bwih0f, 2048 * 512 / 4);
    k_cast<<<512, 256, 0, stream>>>(wih0b, bwih0b, 2048 * 512 / 4);
    k_cast<<<512, 256, 0, stream>>>(wih1f, bwih1f, 2048 * 1024 / 4);
    k_cast<<<512, 256, 0, stream>>>(wih1b, bwih1b, 2048 * 1024 / 4);

    // zero stamped-h buffer once (first-call garbage; stale stamps are
    // layer-tagged; leftover same-layer stamps from a previous replay carry
    // identical deterministic values, so a match is harmless)
    hipMemsetAsync(ws + OFF_HST, 0, 262144, stream);

    // layer 0
    k_proj<<<dim3(128, 16, 2), 256, 0, stream>>>(
        xbf, bwih0f, bwih0b, bih0f, bhh0f, bih0b, bhh0b, xpf, xpb, 512);
    k_rec<<<64, 512, 0, stream>>>(xpf, xpb, whh0f, whh0b, Hd,
                                  hs0, nullptr, fin, 0);

    // layer 1
    k_proj<<<dim3(128, 16, 2), 256, 0, stream>>>(
        hs0, bwih1f, bwih1b, bih1f, bhh1f, bih1b, bhh1b, xpf, xpb, 1024);
    k_rec<<<64, 512, 0, stream>>>(xpf, xpb, whh1f, whh1b, Hd,
                                  nullptr, out, fin, 1);
}

// Round 10
// 5559.612 us; speedup vs baseline: 1.0388x; 1.0388x over previous
//
#include <hip/hip_runtime.h>

// Problem constants
#define BB 32      // batch
#define SS 512     // seq len
#define II 512     // input size
#define HH 512     // hidden
#define GG 2048    // 4*H

typedef unsigned short u16;
typedef unsigned int   u32;
typedef unsigned long long u64;

typedef __attribute__((ext_vector_type(8))) short bf16x8;
typedef __attribute__((ext_vector_type(4))) float f32x4;

__device__ __forceinline__ float b2f(u16 h) {
    return __uint_as_float(((u32)h) << 16);
}
__device__ __forceinline__ u16 f2b(float f) {  // RNE f32 -> bf16
    u32 u = __float_as_uint(f);
    u32 r = (u + 0x7FFFu + ((u >> 16) & 1u)) >> 16;
    return (u16)r;
}

// ---- write-through publish store: bypass L1 (sc0) and local L2 (sc1+nt),
//      line lands CLEAN at the Infinity Cache -> consumer misses need no
//      cross-XCD dirty-probe. 8B store is naturally atomic (aligned).
__device__ __forceinline__ void store8_wt(void* p, u64 v) {
    asm volatile("global_store_dwordx2 %0, %1, off sc0 sc1 nt"
                 :: "v"(p), "v"(v) : "memory");
}

// ---- global_load_lds helper (16B per lane, uniform LDS base + lane*16) ----
#ifndef __has_builtin
#define __has_builtin(x) 0
#endif
#if __has_builtin(__builtin_amdgcn_global_load_lds)
#define HAVE_GLL 1
#else
#define HAVE_GLL 0
#endif

typedef __attribute__((address_space(1))) void as1_void;
typedef __attribute__((address_space(3))) void as3_void;

__device__ __forceinline__ void gload16(const void* g, void* l, int lane) {
#if HAVE_GLL
    __builtin_amdgcn_global_load_lds((as1_void*)g, (as3_void*)l, 16, 0, 0);
#else
    *(bf16x8*)((char*)l + lane * 16) = *(const bf16x8*)g;
#endif
}

// ---------------- convert x: [B][S][I] f32 -> [S][B][I] bf16 ----------------
__global__ void k_convert_x(const float* __restrict__ x, u16* __restrict__ xbf) {
    const int n4 = BB * SS * II / 4;  // 2,097,152
    for (int e4 = blockIdx.x * blockDim.x + threadIdx.x; e4 < n4;
         e4 += gridDim.x * blockDim.x) {
        int e = e4 * 4;
        int s = e >> 14;         // / (B*I = 16384)
        int b = (e >> 9) & 31;
        int i = e & 511;
        float4 v = *(const float4*)(x + (size_t)b * (SS * II) + (size_t)s * II + i);
        ushort4 o;
        o.x = f2b(v.x); o.y = f2b(v.y); o.z = f2b(v.z); o.w = f2b(v.w);
        *(ushort4*)(xbf + (size_t)s * (BB * II) + (size_t)b * II + i) = o;
    }
}

// ---------------- generic f32 -> bf16 cast ----------------
__global__ void k_cast(const float* __restrict__ src, u16* __restrict__ dst, int n4) {
    for (int e4 = blockIdx.x * blockDim.x + threadIdx.x; e4 < n4;
         e4 += gridDim.x * blockDim.x) {
        float4 v = *(const float4*)(src + (size_t)e4 * 4);
        ushort4 o;
        o.x = f2b(v.x); o.y = f2b(v.y); o.z = f2b(v.z); o.w = f2b(v.w);
        *(ushort4*)(dst + (size_t)e4 * 4) = o;
    }
}

// ---------------- input projection GEMM (128x128 tile, BK=64, MFMA bf16) ----
#define BKP 64

__launch_bounds__(256)
__global__ void k_proj(const u16* __restrict__ A,
                       const u16* __restrict__ Wf_, const u16* __restrict__ Wb_,
                       const float* __restrict__ bihf, const float* __restrict__ bhhf,
                       const float* __restrict__ bihb, const float* __restrict__ bhhb,
                       u16* __restrict__ xpf, u16* __restrict__ xpb,
                       int K) {
    const int dir = blockIdx.z;
    const u16* Wm = dir ? Wb_ : Wf_;
    const float* bih = dir ? bihb : bihf;
    const float* bhh = dir ? bhhb : bhhf;
    u16* xp = dir ? xpb : xpf;

    __shared__ __align__(16) u16 As[128 * BKP];
    __shared__ __align__(16) u16 Bs[128 * BKP];

    const int t    = threadIdx.x;
    const int lane = t & 63;
    const int w    = t >> 6;
    const int wm   = w >> 1, wn = w & 1;
    const int m0   = blockIdx.x * 128;
    const int n0   = blockIdx.y * 128;

    f32x4 acc[4][4] = {};

    for (int kt = 0; kt < K; kt += BKP) {
        #pragma unroll
        for (int i = 0; i < 4; ++i) {
            int c   = (w * 4 + i) * 64 + lane;   // physical chunk 0..1023
            int row = c >> 3;
            int lc  = (c & 7) ^ (row & 7);       // logical chunk within row
            int gk  = kt + lc * 8;
            gload16(A  + (size_t)(m0 + row) * K + gk, (char*)As + (w * 4 + i) * 1024, lane);
            gload16(Wm + (size_t)(n0 + row) * K + gk, (char*)Bs + (w * 4 + i) * 1024, lane);
        }
        __syncthreads();

        #pragma unroll
        for (int ks = 0; ks < 2; ++ks) {
            const int kc = ks * 4 + (lane >> 4);
            bf16x8 af[4], bfr[4];
            #pragma unroll
            for (int mi = 0; mi < 4; ++mi) {
                int row = wm * 64 + mi * 16 + (lane & 15);
                af[mi] = *(const bf16x8*)&As[row * BKP + ((kc ^ (row & 7)) << 3)];
            }
            #pragma unroll
            for (int ni = 0; ni < 4; ++ni) {
                int row = wn * 64 + ni * 16 + (lane & 15);
                bfr[ni] = *(const bf16x8*)&Bs[row * BKP + ((kc ^ (row & 7)) << 3)];
            }
            #pragma unroll
            for (int mi = 0; mi < 4; ++mi)
                #pragma unroll
                for (int ni = 0; ni < 4; ++ni)
                    acc[mi][ni] = __builtin_amdgcn_mfma_f32_16x16x32_bf16(
                        af[mi], bfr[ni], acc[mi][ni], 0, 0, 0);
        }
        __syncthreads();
    }

    #pragma unroll
    for (int ni = 0; ni < 4; ++ni) {
        int n = n0 + wn * 64 + ni * 16 + (lane & 15);
        float bias = bih[n] + bhh[n];
        #pragma unroll
        for (int mi = 0; mi < 4; ++mi) {
            #pragma unroll
            for (int r = 0; r < 4; ++r) {
                int m = m0 + wm * 64 + mi * 16 + (lane >> 4) * 4 + r;
                xp[(size_t)m * GG + n] = f2b(acc[mi][ni][r] + bias);
            }
        }
    }
}

// ---------------- persistent recurrence kernel (stamped-word exchange) -----
// EXACT r5 structure (measured-best: 2470 us/layer), ONE change: the publish
// stores are write-through (sc0 sc1 nt) so the stamped words land CLEAN in
// the Infinity Cache instead of dirty in the producer XCD's L2 -- consumer
// poll misses then avoid the cross-XCD dirty-probe round trip.
__launch_bounds__(256)
__global__ void k_rec(const u16* __restrict__ xpf, const u16* __restrict__ xpb,
                      const float* __restrict__ whf, const float* __restrict__ whb,
                      u64* __restrict__ Hd,          // [2 par][2 dir][32][256] u64
                      u16* __restrict__ hs0,         // layer0 out [s][b][1024] bf16
                      float* __restrict__ out,       // layer1 out [b][s][1024] f32
                      float* __restrict__ fin,       // final h (65536 f32) then c
                      int layer) {
    const int bid  = blockIdx.x;
    const int dir  = bid >> 5;
    const int wg   = bid & 31;
    const int j0   = wg * 16;
    const u16*  xp = dir ? xpb : xpf;
    const float* W = dir ? whb : whf;

    const int t    = threadIdx.x;
    const int lane = t & 63;
    const int g    = t >> 6;           // wave id = gate

    __shared__ __align__(16) u16 Wfr[64 * 64 * 8];   // frag-order W slice (64 KB)
    __shared__ __align__(16) u16 hl[32 * 512];       // h tile, XOR-swizzled (32 KB)
    __shared__ float xq[32 * 65];                    // xp slice f32
    __shared__ float gates[4 * 32 * 18];             // per-gate planes, stride 18

    // ---- pack W_hh slice into fragment order (once; validated r3/r5) ----
    for (int it = 0; it < 16; ++it) {
        int task = it * 256 + t;           // 0..4095
        int l    = task & 63;
        int blk  = task >> 6;              // 0..63 = gate*16 + ktile
        int gg   = blk >> 4;
        int kt   = blk & 15;
        const float* src = W + (size_t)(gg * 512 + j0 + (l & 15)) * 512
                             + kt * 32 + (l >> 4) * 8;
        float4 v0 = *(const float4*)src;
        float4 v1 = *(const float4*)(src + 4);
        union { bf16x8 v; u16 a[8]; } u;
        u.a[0] = f2b(v0.x); u.a[1] = f2b(v0.y); u.a[2] = f2b(v0.z); u.a[3] = f2b(v0.w);
        u.a[4] = f2b(v1.x); u.a[5] = f2b(v1.y); u.a[6] = f2b(v1.z); u.a[7] = f2b(v1.w);
        *(bf16x8*)&Wfr[task * 8] = u.v;
    }
    __syncthreads();

    // c-state in registers of epilogue threads (t<128): 4 cols each
    float creg[4] = {0.f, 0.f, 0.f, 0.f};
    const int eb = t >> 2;          // epilogue batch row (0..31)
    const int ej = t & 3;           // epilogue col group -> cols j0+ej*4..+3

    // stage-write address constants: thread t covers (row i, k = 2t, 2t+1)
    const int sc_c   = t >> 2;                 // logical 16B chunk within row
    const int sc_sub = (t & 3) * 4;            // byte within chunk

    for (int s = 0; s < SS; ++s) {
        const int sa = dir ? (SS - 1 - s) : s;

        // ---- A: stage xp slice (plain cached loads; overlaps the poll) ----
        if (t < 128) {
            int b = t & 31, gq = t >> 5;
            const u16* xsrc = xp + (size_t)(sa * 32 + b) * GG + gq * 512 + j0;
            bf16x8 v0 = *(const bf16x8*)xsrc;
            bf16x8 v1 = *(const bf16x8*)(xsrc + 8);
            #pragma unroll
            for (int i = 0; i < 8; ++i) {
                xq[b * 65 + gq * 16 + i]     = b2f((u16)v0[i]);
                xq[b * 65 + gq * 16 + 8 + i] = b2f((u16)v1[i]);
            }
        }

        // ---- B: acquire h(s-1): poll stamped words, then stage to LDS ----
        if (s > 0) {
            const u64* Hrd = Hd + ((size_t)((s & 1) * 2 + dir)) * (32 * 256);
            const u32 tgt = (u32)((layer << 10) | s);
            // light spin on row 0 (covers all 32 producers; cheap pre-wait)
            for (;;) {
                u64 w = __hip_atomic_load(Hrd + t, __ATOMIC_RELAXED,
                                          __HIP_MEMORY_SCOPE_AGENT);
                bool f = (((u32)w & 0xffffu) == tgt) &&
                         ((((u32)(w >> 32)) & 0xffffu) == tgt);
                if (__all(f)) break;
            }
            // full load + verify-all (retry until every word is fresh)
            u64 v[32];
            for (;;) {
                #pragma unroll
                for (int i = 0; i < 32; ++i)
                    v[i] = __hip_atomic_load(Hrd + i * 256 + t, __ATOMIC_RELAXED,
                                             __HIP_MEMORY_SCOPE_AGENT);
                bool ok = true;
                #pragma unroll
                for (int i = 0; i < 32; ++i) {
                    ok = ok && (((u32)v[i] & 0xffffu) == tgt);
                    ok = ok && ((((u32)(v[i] >> 32)) & 0xffffu) == tgt);
                }
                if (__all(ok)) break;
            }
            // stage: row i, bf16 pair (k=2t, 2t+1) -> 4B LDS write (2-way banks)
            #pragma unroll
            for (int i = 0; i < 32; ++i) {
                u32 two = ((u32)(v[i] >> 16) & 0xffffu) | (((u32)(v[i] >> 48)) << 16);
                int off = i * 1024 + ((sc_c ^ (i & 7)) << 4) + sc_sub;
                *(u32*)((char*)hl + off) = two;
            }
        } else {
            #pragma unroll
            for (int i = 0; i < 32; ++i) {
                int off = i * 1024 + ((sc_c ^ (i & 7)) << 4) + sc_sub;
                *(u32*)((char*)hl + off) = 0u;
            }
        }
        __syncthreads();   // (1) hl + xq ready

        // ---- C: MFMA, wave g covers gate g, full K=512 (validated r3) ----
        {
            f32x4 acc0 = {0.f, 0.f, 0.f, 0.f}, acc1 = {0.f, 0.f, 0.f, 0.f};
            const int b0 = lane & 15, q = lane >> 4;
            #pragma unroll
            for (int kt = 0; kt < 16; ++kt) {
                int pc = ((kt << 2) + q) ^ (b0 & 7);
                bf16x8 a0 = *(const bf16x8*)&hl[b0 * 512 + pc * 8];
                bf16x8 a1 = *(const bf16x8*)&hl[(b0 + 16) * 512 + pc * 8];
                bf16x8 Bv = *(const bf16x8*)&Wfr[((g * 16 + kt) * 64 + lane) * 8];
                acc0 = __builtin_amdgcn_mfma_f32_16x16x32_bf16(a0, Bv, acc0, 0, 0, 0);
                acc1 = __builtin_amdgcn_mfma_f32_16x16x32_bf16(a1, Bv, acc1, 0, 0, 0);
            }
            // plane [g][batch][jj], batch-stride 18: row = q*4+r (+16), col = jj
            #pragma unroll
            for (int r = 0; r < 4; ++r) {
                gates[g * 576 + (q * 4 + r) * 18 + b0]      = acc0[r];
                gates[g * 576 + (16 + q * 4 + r) * 18 + b0] = acc1[r];
            }
        }
        __syncthreads();   // (2) gates ready

        // ---- D: elementwise epilogue (t<128): (eb, cols j0+ej*4..+3) ----
        if (t < 128) {
            float hv4[4], cv4[4];
            #pragma unroll
            for (int k = 0; k < 4; ++k) {
                int jj = ej * 4 + k;
                float gi = xq[eb * 65 +      jj] + gates[0 * 576 + eb * 18 + jj];
                float gf = xq[eb * 65 + 16 + jj] + gates[1 * 576 + eb * 18 + jj];
                float gg = xq[eb * 65 + 32 + jj] + gates[2 * 576 + eb * 18 + jj];
                float go = xq[eb * 65 + 48 + jj] + gates[3 * 576 + eb * 18 + jj];
                float ig = 1.f / (1.f + __expf(-gi));
                float fg = 1.f / (1.f + __expf(-gf));
                float gt = tanhf(gg);
                float og = 1.f / (1.f + __expf(-go));
                float c  = fg * creg[k] + ig * gt;
                float h  = og * tanhf(c);
                creg[k] = c; cv4[k] = c; hv4[k] = h;
            }
            // publish stamped h words FIRST, write-through to IC (sc0 sc1 nt)
            u64* Hwr = Hd + ((size_t)(((s + 1) & 1) * 2 + dir)) * (32 * 256);
            const u32 pst = (u32)((layer << 10) | (s + 1));
            u32 w0 = ((u32)f2b(hv4[0]) << 16) | pst;
            u32 w1 = ((u32)f2b(hv4[1]) << 16) | pst;
            u32 w2 = ((u32)f2b(hv4[2]) << 16) | pst;
            u32 w3 = ((u32)f2b(hv4[3]) << 16) | pst;
            u64* dst = Hwr + eb * 256 + ((j0 + ej * 4) >> 1);
            store8_wt(dst,     (u64)w0 | ((u64)w1 << 32));
            store8_wt(dst + 1, (u64)w2 | ((u64)w3 << 32));

            union { u64 q; u16 a[4]; } ho;
            #pragma unroll
            for (int k = 0; k < 4; ++k) ho.a[k] = f2b(hv4[k]);
            if (layer == 0) {
                *(u64*)(hs0 + (size_t)sa * (BB * 1024) + (size_t)eb * 1024
                        + dir * 512 + j0 + ej * 4) = ho.q;
            } else {
                *(float4*)(out + (size_t)eb * (SS * 1024) + (size_t)sa * 1024
                           + dir * 512 + j0 + ej * 4) =
                    make_float4(hv4[0], hv4[1], hv4[2], hv4[3]);
            }
            if (s == SS - 1) {
                int sl = layer * 2 + dir;
                *(float4*)(fin + (size_t)sl * (32 * 512) + eb * 512 + j0 + ej * 4) =
                    make_float4(hv4[0], hv4[1], hv4[2], hv4[3]);
                *(float4*)(fin + 65536 + (size_t)sl * (32 * 512) + eb * 512 + j0 + ej * 4) =
                    make_float4(cv4[0], cv4[1], cv4[2], cv4[3]);
            }
        }
        __syncthreads();   // (3) xq/gates free for next step
    }
}

// ---------------- workspace layout (bytes) ----------------
#define OFF_XBF   ((size_t)0)                       // 16,777,216
#define OFF_HS0   ((size_t)16777216)                // 33,554,432
#define OFF_XPF   ((size_t)50331648)                // 67,108,864
#define OFF_XPB   ((size_t)117440512)               // 67,108,864
#define OFF_WIH0F ((size_t)184549376)               // 2,097,152
#define OFF_WIH0B ((size_t)186646528)               // 2,097,152
#define OFF_WIH1F ((size_t)188743680)               // 4,194,304
#define OFF_WIH1B ((size_t)192937984)               // 4,194,304
#define OFF_HST   ((size_t)197132288)               // 262,144 (stamped h)

extern "C" void kernel_launch(void* const* d_in, const int* in_sizes, int n_in,
                              void* d_out, int out_size, void* d_ws, size_t ws_size,
                              hipStream_t stream) {
    const float* x      = (const float*)d_in[0];
    const float* wih0f  = (const float*)d_in[1];
    const float* whh0f  = (const float*)d_in[2];
    const float* bih0f  = (const float*)d_in[3];
    const float* bhh0f  = (const float*)d_in[4];
    const float* wih0b  = (const float*)d_in[5];
    const float* whh0b  = (const float*)d_in[6];
    const float* bih0b  = (const float*)d_in[7];
    const float* bhh0b  = (const float*)d_in[8];
    const float* wih1f  = (const float*)d_in[9];
    const float* whh1f  = (const float*)d_in[10];
    const float* bih1f  = (const float*)d_in[11];
    const float* bhh1f  = (const float*)d_in[12];
    const float* wih1b  = (const float*)d_in[13];
    const float* whh1b  = (const float*)d_in[14];
    const float* bih1b  = (const float*)d_in[15];
    const float* bhh1b  = (const float*)d_in[16];

    float* out = (float*)d_out;
    char* ws = (char*)d_ws;

    u16* xbf    = (u16*)(ws + OFF_XBF);
    u16* hs0    = (u16*)(ws + OFF_HS0);
    u16* xpf    = (u16*)(ws + OFF_XPF);
    u16* xpb    = (u16*)(ws + OFF_XPB);
    u16* bwih0f = (u16*)(ws + OFF_WIH0F);
    u16* bwih0b = (u16*)(ws + OFF_WIH0B);
    u16* bwih1f = (u16*)(ws + OFF_WIH1F);
    u16* bwih1b = (u16*)(ws + OFF_WIH1B);
    u64* Hd     = (u64*)(ws + OFF_HST);
    float* fin  = out + 16777216;   // final h stack, then c stack at +65536

    // converts
    k_convert_x<<<1024, 256, 0, stream>>>(x, xbf);
    k_cast<<<512, 256, 0, stream>>>(wih0f, bwih0f, 2048 * 512 / 4);
    k_cast<<<512, 256, 0, stream>>>(wih0b, bwih0b, 2048 * 512 / 4);
    k_cast<<<512, 256, 0, stream>>>(wih1f, bwih1f, 2048 * 1024 / 4);
    k_cast<<<512, 256, 0, stream>>>(wih1b, bwih1b, 2048 * 1024 / 4);

    // zero stamped-h buffer once (first-call garbage; stale stamps are
    // layer-tagged; leftover same-layer stamps from a previous replay carry
    // identical deterministic values, so a match is harmless)
    hipMemsetAsync(ws + OFF_HST, 0, 262144, stream);

    // layer 0
    k_proj<<<dim3(128, 16, 2), 256, 0, stream>>>(
        xbf, bwih0f, bwih0b, bih0f, bhh0f, bih0b, bhh0b, xpf, xpb, 512);
    k_rec<<<64, 256, 0, stream>>>(xpf, xpb, whh0f, whh0b, Hd,
                                  hs0, nullptr, fin, 0);

    // layer 1
    k_proj<<<dim3(128, 16, 2), 256, 0, stream>>>(
        hs0, bwih1f, bwih1b, bih1f, bhh1f, bih1b, bhh1b, xpf, xpb, 1024);
    k_rec<<<64, 256, 0, stream>>>(xpf, xpb, whh1f, whh1b, Hd,
                                  nullptr, out, fin, 1);
}

// Round 11
// 5427.526 us; speedup vs baseline: 1.0640x; 1.0243x over previous
//
#include <hip/hip_runtime.h>

// Problem constants
#define BB 32      // batch
#define SS 512     // seq len
#define II 512     // input size
#define HH 512     // hidden
#define GG 2048    // 4*H

typedef unsigned short u16;
typedef unsigned int   u32;
typedef unsigned long long u64;

typedef __attribute__((ext_vector_type(8))) short bf16x8;
typedef __attribute__((ext_vector_type(4))) float f32x4;

__device__ __forceinline__ float b2f(u16 h) {
    return __uint_as_float(((u32)h) << 16);
}
__device__ __forceinline__ u16 f2b(float f) {  // RNE f32 -> bf16
    u32 u = __float_as_uint(f);
    u32 r = (u + 0x7FFFu + ((u >> 16) & 1u)) >> 16;
    return (u16)r;
}

// ---- global_load_lds helper (16B per lane, uniform LDS base + lane*16) ----
#ifndef __has_builtin
#define __has_builtin(x) 0
#endif
#if __has_builtin(__builtin_amdgcn_global_load_lds)
#define HAVE_GLL 1
#else
#define HAVE_GLL 0
#endif

typedef __attribute__((address_space(1))) void as1_void;
typedef __attribute__((address_space(3))) void as3_void;

__device__ __forceinline__ void gload16(const void* g, void* l, int lane) {
#if HAVE_GLL
    __builtin_amdgcn_global_load_lds((as1_void*)g, (as3_void*)l, 16, 0, 0);
#else
    *(bf16x8*)((char*)l + lane * 16) = *(const bf16x8*)g;
#endif
}

// ---------------- convert x: [B][S][I] f32 -> [S][B][I] bf16 ----------------
__global__ void k_convert_x(const float* __restrict__ x, u16* __restrict__ xbf) {
    const int n4 = BB * SS * II / 4;  // 2,097,152
    for (int e4 = blockIdx.x * blockDim.x + threadIdx.x; e4 < n4;
         e4 += gridDim.x * blockDim.x) {
        int e = e4 * 4;
        int s = e >> 14;         // / (B*I = 16384)
        int b = (e >> 9) & 31;
        int i = e & 511;
        float4 v = *(const float4*)(x + (size_t)b * (SS * II) + (size_t)s * II + i);
        ushort4 o;
        o.x = f2b(v.x); o.y = f2b(v.y); o.z = f2b(v.z); o.w = f2b(v.w);
        *(ushort4*)(xbf + (size_t)s * (BB * II) + (size_t)b * II + i) = o;
    }
}

// ---------------- generic f32 -> bf16 cast ----------------
__global__ void k_cast(const float* __restrict__ src, u16* __restrict__ dst, int n4) {
    for (int e4 = blockIdx.x * blockDim.x + threadIdx.x; e4 < n4;
         e4 += gridDim.x * blockDim.x) {
        float4 v = *(const float4*)(src + (size_t)e4 * 4);
        ushort4 o;
        o.x = f2b(v.x); o.y = f2b(v.y); o.z = f2b(v.z); o.w = f2b(v.w);
        *(ushort4*)(dst + (size_t)e4 * 4) = o;
    }
}

// ---------------- input projection GEMM (128x128 tile, BK=64, MFMA bf16) ----
#define BKP 64

__launch_bounds__(256)
__global__ void k_proj(const u16* __restrict__ A,
                       const u16* __restrict__ Wf_, const u16* __restrict__ Wb_,
                       const float* __restrict__ bihf, const float* __restrict__ bhhf,
                       const float* __restrict__ bihb, const float* __restrict__ bhhb,
                       u16* __restrict__ xpf, u16* __restrict__ xpb,
                       int K) {
    const int dir = blockIdx.z;
    const u16* Wm = dir ? Wb_ : Wf_;
    const float* bih = dir ? bihb : bihf;
    const float* bhh = dir ? bhhb : bhhf;
    u16* xp = dir ? xpb : xpf;

    __shared__ __align__(16) u16 As[128 * BKP];
    __shared__ __align__(16) u16 Bs[128 * BKP];

    const int t    = threadIdx.x;
    const int lane = t & 63;
    const int w    = t >> 6;
    const int wm   = w >> 1, wn = w & 1;
    const int m0   = blockIdx.x * 128;
    const int n0   = blockIdx.y * 128;

    f32x4 acc[4][4] = {};

    for (int kt = 0; kt < K; kt += BKP) {
        #pragma unroll
        for (int i = 0; i < 4; ++i) {
            int c   = (w * 4 + i) * 64 + lane;   // physical chunk 0..1023
            int row = c >> 3;
            int lc  = (c & 7) ^ (row & 7);       // logical chunk within row
            int gk  = kt + lc * 8;
            gload16(A  + (size_t)(m0 + row) * K + gk, (char*)As + (w * 4 + i) * 1024, lane);
            gload16(Wm + (size_t)(n0 + row) * K + gk, (char*)Bs + (w * 4 + i) * 1024, lane);
        }
        __syncthreads();

        #pragma unroll
        for (int ks = 0; ks < 2; ++ks) {
            const int kc = ks * 4 + (lane >> 4);
            bf16x8 af[4], bfr[4];
            #pragma unroll
            for (int mi = 0; mi < 4; ++mi) {
                int row = wm * 64 + mi * 16 + (lane & 15);
                af[mi] = *(const bf16x8*)&As[row * BKP + ((kc ^ (row & 7)) << 3)];
            }
            #pragma unroll
            for (int ni = 0; ni < 4; ++ni) {
                int row = wn * 64 + ni * 16 + (lane & 15);
                bfr[ni] = *(const bf16x8*)&Bs[row * BKP + ((kc ^ (row & 7)) << 3)];
            }
            #pragma unroll
            for (int mi = 0; mi < 4; ++mi)
                #pragma unroll
                for (int ni = 0; ni < 4; ++ni)
                    acc[mi][ni] = __builtin_amdgcn_mfma_f32_16x16x32_bf16(
                        af[mi], bfr[ni], acc[mi][ni], 0, 0, 0);
        }
        __syncthreads();
    }

    #pragma unroll
    for (int ni = 0; ni < 4; ++ni) {
        int n = n0 + wn * 64 + ni * 16 + (lane & 15);
        float bias = bih[n] + bhh[n];
        #pragma unroll
        for (int mi = 0; mi < 4; ++mi) {
            #pragma unroll
            for (int r = 0; r < 4; ++r) {
                int m = m0 + wm * 64 + mi * 16 + (lane >> 4) * 4 + r;
                xp[(size_t)m * GG + n] = f2b(acc[mi][ni][r] + bias);
            }
        }
    }
}

// ---------------- persistent recurrence kernel (stamped-word exchange) -----
// r5 structure (measured-best) with the critical path stripped to
// poll -> stage -> MFMA -> epilogue/publish:
//  - xq double-buffered; xp(s+1) PREFETCHED into registers during the MFMA
//    window and converted during the epilogue phase -> loop top goes straight
//    to the poll (xp latency off the serial chain)
//  - barrier(3) dropped (hazards closed by dbuf xq + barrier(1) gating)
//  - publish: plain relaxed agent-scope atomic stores (r5-proven)
__launch_bounds__(256)
__global__ void k_rec(const u16* __restrict__ xpf, const u16* __restrict__ xpb,
                      const float* __restrict__ whf, const float* __restrict__ whb,
                      u64* __restrict__ Hd,          // [2 par][2 dir][32][256] u64
                      u16* __restrict__ hs0,         // layer0 out [s][b][1024] bf16
                      float* __restrict__ out,       // layer1 out [b][s][1024] f32
                      float* __restrict__ fin,       // final h (65536 f32) then c
                      int layer) {
    const int bid  = blockIdx.x;
    const int dir  = bid >> 5;
    const int wg   = bid & 31;
    const int j0   = wg * 16;
    const u16*  xp = dir ? xpb : xpf;
    const float* W = dir ? whb : whf;

    const int t    = threadIdx.x;
    const int lane = t & 63;
    const int g    = t >> 6;           // wave id = gate

    __shared__ __align__(16) u16 Wfr[64 * 64 * 8];   // frag-order W slice (64 KB)
    __shared__ __align__(16) u16 hl[32 * 512];       // h tile, XOR-swizzled (32 KB)
    __shared__ float xq[2][32 * 65];                 // xp slice f32, double-buffered
    __shared__ float gates[4 * 32 * 18];             // per-gate planes, stride 18

    // ---- pack W_hh slice into fragment order (once; validated r3/r5) ----
    for (int it = 0; it < 16; ++it) {
        int task = it * 256 + t;           // 0..4095
        int l    = task & 63;
        int blk  = task >> 6;              // 0..63 = gate*16 + ktile
        int gg   = blk >> 4;
        int kt   = blk & 15;
        const float* src = W + (size_t)(gg * 512 + j0 + (l & 15)) * 512
                             + kt * 32 + (l >> 4) * 8;
        float4 v0 = *(const float4*)src;
        float4 v1 = *(const float4*)(src + 4);
        union { bf16x8 v; u16 a[8]; } u;
        u.a[0] = f2b(v0.x); u.a[1] = f2b(v0.y); u.a[2] = f2b(v0.z); u.a[3] = f2b(v0.w);
        u.a[4] = f2b(v1.x); u.a[5] = f2b(v1.y); u.a[6] = f2b(v1.z); u.a[7] = f2b(v1.w);
        *(bf16x8*)&Wfr[task * 8] = u.v;
    }

    // xp prefetch mapping: thread t -> (batch pb, gate pg, half ph) : 8 bf16
    const int pb = t >> 3;
    const int pg = (t & 7) >> 1;
    const int ph = t & 1;

    // ---- stage xq[0] for s = 0 (pre-loop; off the steady-state path) ----
    {
        const int sa0 = dir ? (SS - 1) : 0;
        bf16x8 v0 = *(const bf16x8*)(xp + (size_t)(sa0 * 32 + pb) * GG
                                     + pg * 512 + j0 + ph * 8);
        float* xd = &xq[0][pb * 65 + pg * 16 + ph * 8];
        #pragma unroll
        for (int i = 0; i < 8; ++i) xd[i] = b2f((u16)v0[i]);
    }
    __syncthreads();

    // c-state in registers of epilogue threads (t<128): 4 cols each
    float creg[4] = {0.f, 0.f, 0.f, 0.f};
    const int eb = t >> 2;          // epilogue batch row (0..31)
    const int ej = t & 3;           // epilogue col group -> cols j0+ej*4..+3

    // stage-write address constants: thread t covers (row i, k = 2t, 2t+1)
    const int sc_c   = t >> 2;                 // logical 16B chunk within row
    const int sc_sub = (t & 3) * 4;            // byte within chunk

    for (int s = 0; s < SS; ++s) {
        const int sa = dir ? (SS - 1 - s) : s;

        // ---- P: acquire h(s-1): poll stamped words, then stage to LDS ----
        if (s > 0) {
            const u64* Hrd = Hd + ((size_t)((s & 1) * 2 + dir)) * (32 * 256);
            const u32 tgt = (u32)((layer << 10) | s);
            // light spin on row 0 (covers all 32 producers; cheap pre-wait)
            for (;;) {
                u64 w = __hip_atomic_load(Hrd + t, __ATOMIC_RELAXED,
                                          __HIP_MEMORY_SCOPE_AGENT);
                bool f = (((u32)w & 0xffffu) == tgt) &&
                         ((((u32)(w >> 32)) & 0xffffu) == tgt);
                if (__all(f)) break;
            }
            // full load + verify-all (retry until every word is fresh)
            u64 v[32];
            for (;;) {
                #pragma unroll
                for (int i = 0; i < 32; ++i)
                    v[i] = __hip_atomic_load(Hrd + i * 256 + t, __ATOMIC_RELAXED,
                                             __HIP_MEMORY_SCOPE_AGENT);
                bool ok = true;
                #pragma unroll
                for (int i = 0; i < 32; ++i) {
                    ok = ok && (((u32)v[i] & 0xffffu) == tgt);
                    ok = ok && ((((u32)(v[i] >> 32)) & 0xffffu) == tgt);
                }
                if (__all(ok)) break;
            }
            // stage: row i, bf16 pair (k=2t, 2t+1) -> 4B LDS write (2-way banks)
            #pragma unroll
            for (int i = 0; i < 32; ++i) {
                u32 two = ((u32)(v[i] >> 16) & 0xffffu) | (((u32)(v[i] >> 48)) << 16);
                int off = i * 1024 + ((sc_c ^ (i & 7)) << 4) + sc_sub;
                *(u32*)((char*)hl + off) = two;
            }
        } else {
            #pragma unroll
            for (int i = 0; i < 32; ++i) {
                int off = i * 1024 + ((sc_c ^ (i & 7)) << 4) + sc_sub;
                *(u32*)((char*)hl + off) = 0u;
            }
        }
        __syncthreads();   // (1) hl ready

        // ---- C: issue xp(s+1) prefetch, then MFMA (loads fly under MFMA) ----
        bf16x8 pref;
        if (s + 1 < SS) {
            const int sa1 = dir ? (SS - 2 - s) : (s + 1);
            pref = *(const bf16x8*)(xp + (size_t)(sa1 * 32 + pb) * GG
                                    + pg * 512 + j0 + ph * 8);
        }
        {
            f32x4 acc0 = {0.f, 0.f, 0.f, 0.f}, acc1 = {0.f, 0.f, 0.f, 0.f};
            const int b0 = lane & 15, q = lane >> 4;
            #pragma unroll
            for (int kt = 0; kt < 16; ++kt) {
                int pc = ((kt << 2) + q) ^ (b0 & 7);
                bf16x8 a0 = *(const bf16x8*)&hl[b0 * 512 + pc * 8];
                bf16x8 a1 = *(const bf16x8*)&hl[(b0 + 16) * 512 + pc * 8];
                bf16x8 Bv = *(const bf16x8*)&Wfr[((g * 16 + kt) * 64 + lane) * 8];
                acc0 = __builtin_amdgcn_mfma_f32_16x16x32_bf16(a0, Bv, acc0, 0, 0, 0);
                acc1 = __builtin_amdgcn_mfma_f32_16x16x32_bf16(a1, Bv, acc1, 0, 0, 0);
            }
            // plane [g][batch][jj], batch-stride 18: row = q*4+r (+16), col = jj
            #pragma unroll
            for (int r = 0; r < 4; ++r) {
                gates[g * 576 + (q * 4 + r) * 18 + b0]      = acc0[r];
                gates[g * 576 + (16 + q * 4 + r) * 18 + b0] = acc1[r];
            }
        }
        __syncthreads();   // (2) gates ready

        // ---- E: epilogue (t<128) + xq[(s+1)&1] fill (all threads) ----
        if (t < 128) {
            float hv4[4], cv4[4];
            #pragma unroll
            for (int k = 0; k < 4; ++k) {
                int jj = ej * 4 + k;
                float gi = xq[s & 1][eb * 65 +      jj] + gates[0 * 576 + eb * 18 + jj];
                float gf = xq[s & 1][eb * 65 + 16 + jj] + gates[1 * 576 + eb * 18 + jj];
                float gg = xq[s & 1][eb * 65 + 32 + jj] + gates[2 * 576 + eb * 18 + jj];
                float go = xq[s & 1][eb * 65 + 48 + jj] + gates[3 * 576 + eb * 18 + jj];
                float ig = 1.f / (1.f + __expf(-gi));
                float fg = 1.f / (1.f + __expf(-gf));
                float gt = tanhf(gg);
                float og = 1.f / (1.f + __expf(-go));
                float c  = fg * creg[k] + ig * gt;
                float h  = og * tanhf(c);
                creg[k] = c; cv4[k] = c; hv4[k] = h;
            }
            // publish stamped h words FIRST (critical path), parity ping-pong
            u64* Hwr = Hd + ((size_t)(((s + 1) & 1) * 2 + dir)) * (32 * 256);
            const u32 pst = (u32)((layer << 10) | (s + 1));
            u32 w0 = ((u32)f2b(hv4[0]) << 16) | pst;
            u32 w1 = ((u32)f2b(hv4[1]) << 16) | pst;
            u32 w2 = ((u32)f2b(hv4[2]) << 16) | pst;
            u32 w3 = ((u32)f2b(hv4[3]) << 16) | pst;
            u64* dst = Hwr + eb * 256 + ((j0 + ej * 4) >> 1);
            __hip_atomic_store(dst,     (u64)w0 | ((u64)w1 << 32),
                               __ATOMIC_RELAXED, __HIP_MEMORY_SCOPE_AGENT);
            __hip_atomic_store(dst + 1, (u64)w2 | ((u64)w3 << 32),
                               __ATOMIC_RELAXED, __HIP_MEMORY_SCOPE_AGENT);

            union { u64 q; u16 a[4]; } ho;
            #pragma unroll
            for (int k = 0; k < 4; ++k) ho.a[k] = f2b(hv4[k]);
            if (layer == 0) {
                *(u64*)(hs0 + (size_t)sa * (BB * 1024) + (size_t)eb * 1024
                        + dir * 512 + j0 + ej * 4) = ho.q;
            } else {
                *(float4*)(out + (size_t)eb * (SS * 1024) + (size_t)sa * 1024
                           + dir * 512 + j0 + ej * 4) =
                    make_float4(hv4[0], hv4[1], hv4[2], hv4[3]);
            }
            if (s == SS - 1) {
                int sl = layer * 2 + dir;
                *(float4*)(fin + (size_t)sl * (32 * 512) + eb * 512 + j0 + ej * 4) =
                    make_float4(hv4[0], hv4[1], hv4[2], hv4[3]);
                *(float4*)(fin + 65536 + (size_t)sl * (32 * 512) + eb * 512 + j0 + ej * 4) =
                    make_float4(cv4[0], cv4[1], cv4[2], cv4[3]);
            }
        }
        // all threads: convert prefetched xp into the OTHER xq buffer
        if (s + 1 < SS) {
            float* xd = &xq[(s + 1) & 1][pb * 65 + pg * 16 + ph * 8];
            #pragma unroll
            for (int i = 0; i < 8; ++i) xd[i] = b2f((u16)pref[i]);
        }
        // no barrier(3): xq dbuf'd; gates/hl next-writes gated by barrier(1)
        // of step s+1, which epilogue waves must also reach.
    }
}

// ---------------- workspace layout (bytes) ----------------
#define OFF_XBF   ((size_t)0)                       // 16,777,216
#define OFF_HS0   ((size_t)16777216)                // 33,554,432
#define OFF_XPF   ((size_t)50331648)                // 67,108,864
#define OFF_XPB   ((size_t)117440512)               // 67,108,864
#define OFF_WIH0F ((size_t)184549376)               // 2,097,152
#define OFF_WIH0B ((size_t)186646528)               // 2,097,152
#define OFF_WIH1F ((size_t)188743680)               // 4,194,304
#define OFF_WIH1B ((size_t)192937984)               // 4,194,304
#define OFF_HST   ((size_t)197132288)               // 262,144 (stamped h)

extern "C" void kernel_launch(void* const* d_in, const int* in_sizes, int n_in,
                              void* d_out, int out_size, void* d_ws, size_t ws_size,
                              hipStream_t stream) {
    const float* x      = (const float*)d_in[0];
    const float* wih0f  = (const float*)d_in[1];
    const float* whh0f  = (const float*)d_in[2];
    const float* bih0f  = (const float*)d_in[3];
    const float* bhh0f  = (const float*)d_in[4];
    const float* wih0b  = (const float*)d_in[5];
    const float* whh0b  = (const float*)d_in[6];
    const float* bih0b  = (const float*)d_in[7];
    const float* bhh0b  = (const float*)d_in[8];
    const float* wih1f  = (const float*)d_in[9];
    const float* whh1f  = (const float*)d_in[10];
    const float* bih1f  = (const float*)d_in[11];
    const float* bhh1f  = (const float*)d_in[12];
    const float* wih1b  = (const float*)d_in[13];
    const float* whh1b  = (const float*)d_in[14];
    const float* bih1b  = (const float*)d_in[15];
    const float* bhh1b  = (const float*)d_in[16];

    float* out = (float*)d_out;
    char* ws = (char*)d_ws;

    u16* xbf    = (u16*)(ws + OFF_XBF);
    u16* hs0    = (u16*)(ws + OFF_HS0);
    u16* xpf    = (u16*)(ws + OFF_XPF);
    u16* xpb    = (u16*)(ws + OFF_XPB);
    u16* bwih0f = (u16*)(ws + OFF_WIH0F);
    u16* bwih0b = (u16*)(ws + OFF_WIH0B);
    u16* bwih1f = (u16*)(ws + OFF_WIH1F);
    u16* bwih1b = (u16*)(ws + OFF_WIH1B);
    u64* Hd     = (u64*)(ws + OFF_HST);
    float* fin  = out + 16777216;   // final h stack, then c stack at +65536

    // converts
    k_convert_x<<<1024, 256, 0, stream>>>(x, xbf);
    k_cast<<<512, 256, 0, stream>>>(wih0f, bwih0f, 2048 * 512 / 4);
    k_cast<<<512, 256, 0, stream>>>(wih0b, bwih0b, 2048 * 512 / 4);
    k_cast<<<512, 256, 0, stream>>>(wih1f, bwih1f, 2048 * 1024 / 4);
    k_cast<<<512, 256, 0, stream>>>(wih1b, bwih1b, 2048 * 1024 / 4);

    // zero stamped-h buffer once (first-call garbage; stale stamps are
    // layer-tagged; leftover same-layer stamps from a previous replay carry
    // identical deterministic values, so a match is harmless)
    hipMemsetAsync(ws + OFF_HST, 0, 262144, stream);

    // layer 0
    k_proj<<<dim3(128, 16, 2), 256, 0, stream>>>(
        xbf, bwih0f, bwih0b, bih0f, bhh0f, bih0b, bhh0b, xpf, xpb, 512);
    k_rec<<<64, 256, 0, stream>>>(xpf, xpb, whh0f, whh0b, Hd,
                                  hs0, nullptr, fin, 0);

    // layer 1
    k_proj<<<dim3(128, 16, 2), 256, 0, stream>>>(
        hs0, bwih1f, bwih1b, bih1f, bhh1f, bih1b, bhh1b, xpf, xpb, 1024);
    k_rec<<<64, 256, 0, stream>>>(xpf, xpb, whh1f, whh1b, Hd,
                                  nullptr, out, fin, 1);
}

// Round 12
// 5122.021 us; speedup vs baseline: 1.1275x; 1.0596x over previous
//
#include <hip/hip_runtime.h>

// Problem constants
#define BB 32      // batch
#define SS 512     // seq len
#define II 512     // input size
#define HH 512     // hidden
#define GG 2048    // 4*H

typedef unsigned short u16;
typedef unsigned int   u32;
typedef unsigned long long u64;

typedef __attribute__((ext_vector_type(8))) short bf16x8;
typedef __attribute__((ext_vector_type(4))) float f32x4;

__device__ __forceinline__ float b2f(u16 h) {
    return __uint_as_float(((u32)h) << 16);
}
__device__ __forceinline__ u16 f2b(float f) {  // RNE f32 -> bf16
    u32 u = __float_as_uint(f);
    u32 r = (u + 0x7FFFu + ((u >> 16) & 1u)) >> 16;
    return (u16)r;
}

// ---- global_load_lds helper (16B per lane, uniform LDS base + lane*16) ----
#ifndef __has_builtin
#define __has_builtin(x) 0
#endif
#if __has_builtin(__builtin_amdgcn_global_load_lds)
#define HAVE_GLL 1
#else
#define HAVE_GLL 0
#endif

typedef __attribute__((address_space(1))) void as1_void;
typedef __attribute__((address_space(3))) void as3_void;

__device__ __forceinline__ void gload16(const void* g, void* l, int lane) {
#if HAVE_GLL
    __builtin_amdgcn_global_load_lds((as1_void*)g, (as3_void*)l, 16, 0, 0);
#else
    *(bf16x8*)((char*)l + lane * 16) = *(const bf16x8*)g;
#endif
}

// ---------------- convert x: [B][S][I] f32 -> [S][B][I] bf16 ----------------
__global__ void k_convert_x(const float* __restrict__ x, u16* __restrict__ xbf) {
    const int n4 = BB * SS * II / 4;  // 2,097,152
    for (int e4 = blockIdx.x * blockDim.x + threadIdx.x; e4 < n4;
         e4 += gridDim.x * blockDim.x) {
        int e = e4 * 4;
        int s = e >> 14;         // / (B*I = 16384)
        int b = (e >> 9) & 31;
        int i = e & 511;
        float4 v = *(const float4*)(x + (size_t)b * (SS * II) + (size_t)s * II + i);
        ushort4 o;
        o.x = f2b(v.x); o.y = f2b(v.y); o.z = f2b(v.z); o.w = f2b(v.w);
        *(ushort4*)(xbf + (size_t)s * (BB * II) + (size_t)b * II + i) = o;
    }
}

// ---------------- generic f32 -> bf16 cast ----------------
__global__ void k_cast(const float* __restrict__ src, u16* __restrict__ dst, int n4) {
    for (int e4 = blockIdx.x * blockDim.x + threadIdx.x; e4 < n4;
         e4 += gridDim.x * blockDim.x) {
        float4 v = *(const float4*)(src + (size_t)e4 * 4);
        ushort4 o;
        o.x = f2b(v.x); o.y = f2b(v.y); o.z = f2b(v.z); o.w = f2b(v.w);
        *(ushort4*)(dst + (size_t)e4 * 4) = o;
    }
}

// ---------------- input projection GEMM (128x128 tile, BK=64, MFMA bf16) ----
#define BKP 64

__launch_bounds__(256)
__global__ void k_proj(const u16* __restrict__ A,
                       const u16* __restrict__ Wf_, const u16* __restrict__ Wb_,
                       const float* __restrict__ bihf, const float* __restrict__ bhhf,
                       const float* __restrict__ bihb, const float* __restrict__ bhhb,
                       u16* __restrict__ xpf, u16* __restrict__ xpb,
                       int K) {
    const int dir = blockIdx.z;
    const u16* Wm = dir ? Wb_ : Wf_;
    const float* bih = dir ? bihb : bihf;
    const float* bhh = dir ? bhhb : bhhf;
    u16* xp = dir ? xpb : xpf;

    __shared__ __align__(16) u16 As[128 * BKP];
    __shared__ __align__(16) u16 Bs[128 * BKP];

    const int t    = threadIdx.x;
    const int lane = t & 63;
    const int w    = t >> 6;
    const int wm   = w >> 1, wn = w & 1;
    const int m0   = blockIdx.x * 128;
    const int n0   = blockIdx.y * 128;

    f32x4 acc[4][4] = {};

    for (int kt = 0; kt < K; kt += BKP) {
        #pragma unroll
        for (int i = 0; i < 4; ++i) {
            int c   = (w * 4 + i) * 64 + lane;   // physical chunk 0..1023
            int row = c >> 3;
            int lc  = (c & 7) ^ (row & 7);       // logical chunk within row
            int gk  = kt + lc * 8;
            gload16(A  + (size_t)(m0 + row) * K + gk, (char*)As + (w * 4 + i) * 1024, lane);
            gload16(Wm + (size_t)(n0 + row) * K + gk, (char*)Bs + (w * 4 + i) * 1024, lane);
        }
        __syncthreads();

        #pragma unroll
        for (int ks = 0; ks < 2; ++ks) {
            const int kc = ks * 4 + (lane >> 4);
            bf16x8 af[4], bfr[4];
            #pragma unroll
            for (int mi = 0; mi < 4; ++mi) {
                int row = wm * 64 + mi * 16 + (lane & 15);
                af[mi] = *(const bf16x8*)&As[row * BKP + ((kc ^ (row & 7)) << 3)];
            }
            #pragma unroll
            for (int ni = 0; ni < 4; ++ni) {
                int row = wn * 64 + ni * 16 + (lane & 15);
                bfr[ni] = *(const bf16x8*)&Bs[row * BKP + ((kc ^ (row & 7)) << 3)];
            }
            #pragma unroll
            for (int mi = 0; mi < 4; ++mi)
                #pragma unroll
                for (int ni = 0; ni < 4; ++ni)
                    acc[mi][ni] = __builtin_amdgcn_mfma_f32_16x16x32_bf16(
                        af[mi], bfr[ni], acc[mi][ni], 0, 0, 0);
        }
        __syncthreads();
    }

    #pragma unroll
    for (int ni = 0; ni < 4; ++ni) {
        int n = n0 + wn * 64 + ni * 16 + (lane & 15);
        float bias = bih[n] + bhh[n];
        #pragma unroll
        for (int mi = 0; mi < 4; ++mi) {
            #pragma unroll
            for (int r = 0; r < 4; ++r) {
                int m = m0 + wm * 64 + mi * 16 + (lane >> 4) * 4 + r;
                xp[(size_t)m * GG + n] = f2b(acc[mi][ni][r] + bias);
            }
        }
    }
}

// ---------------- persistent recurrence kernel (stamped-word exchange) -----
// EXACT r5 structure (measured-best: 2477 us/layer) with ONE change: the
// two-phase poll (light spin on row 0, THEN full load+verify) is collapsed
// into a SINGLE full load+verify loop -- detect and consume in one pipelined
// IC pass instead of two serial round trips.
__launch_bounds__(256)
__global__ void k_rec(const u16* __restrict__ xpf, const u16* __restrict__ xpb,
                      const float* __restrict__ whf, const float* __restrict__ whb,
                      u64* __restrict__ Hd,          // [2 par][2 dir][32][256] u64
                      u16* __restrict__ hs0,         // layer0 out [s][b][1024] bf16
                      float* __restrict__ out,       // layer1 out [b][s][1024] f32
                      float* __restrict__ fin,       // final h (65536 f32) then c
                      int layer) {
    const int bid  = blockIdx.x;
    const int dir  = bid >> 5;
    const int wg   = bid & 31;
    const int j0   = wg * 16;
    const u16*  xp = dir ? xpb : xpf;
    const float* W = dir ? whb : whf;

    const int t    = threadIdx.x;
    const int lane = t & 63;
    const int g    = t >> 6;           // wave id = gate

    __shared__ __align__(16) u16 Wfr[64 * 64 * 8];   // frag-order W slice (64 KB)
    __shared__ __align__(16) u16 hl[32 * 512];       // h tile, XOR-swizzled (32 KB)
    __shared__ float xq[32 * 65];                    // xp slice f32
    __shared__ float gates[4 * 32 * 18];             // per-gate planes, stride 18

    // ---- pack W_hh slice into fragment order (once; validated r3/r5) ----
    for (int it = 0; it < 16; ++it) {
        int task = it * 256 + t;           // 0..4095
        int l    = task & 63;
        int blk  = task >> 6;              // 0..63 = gate*16 + ktile
        int gg   = blk >> 4;
        int kt   = blk & 15;
        const float* src = W + (size_t)(gg * 512 + j0 + (l & 15)) * 512
                             + kt * 32 + (l >> 4) * 8;
        float4 v0 = *(const float4*)src;
        float4 v1 = *(const float4*)(src + 4);
        union { bf16x8 v; u16 a[8]; } u;
        u.a[0] = f2b(v0.x); u.a[1] = f2b(v0.y); u.a[2] = f2b(v0.z); u.a[3] = f2b(v0.w);
        u.a[4] = f2b(v1.x); u.a[5] = f2b(v1.y); u.a[6] = f2b(v1.z); u.a[7] = f2b(v1.w);
        *(bf16x8*)&Wfr[task * 8] = u.v;
    }
    __syncthreads();

    // c-state in registers of epilogue threads (t<128): 4 cols each
    float creg[4] = {0.f, 0.f, 0.f, 0.f};
    const int eb = t >> 2;          // epilogue batch row (0..31)
    const int ej = t & 3;           // epilogue col group -> cols j0+ej*4..+3

    // stage-write address constants: thread t covers (row i, k = 2t, 2t+1)
    const int sc_c   = t >> 2;                 // logical 16B chunk within row
    const int sc_sub = (t & 3) * 4;            // byte within chunk

    for (int s = 0; s < SS; ++s) {
        const int sa = dir ? (SS - 1 - s) : s;

        // ---- A: stage xp slice (plain cached loads; overlaps the poll) ----
        if (t < 128) {
            int b = t & 31, gq = t >> 5;
            const u16* xsrc = xp + (size_t)(sa * 32 + b) * GG + gq * 512 + j0;
            bf16x8 v0 = *(const bf16x8*)xsrc;
            bf16x8 v1 = *(const bf16x8*)(xsrc + 8);
            #pragma unroll
            for (int i = 0; i < 8; ++i) {
                xq[b * 65 + gq * 16 + i]     = b2f((u16)v0[i]);
                xq[b * 65 + gq * 16 + 8 + i] = b2f((u16)v1[i]);
            }
        }

        // ---- B: acquire h(s-1): SINGLE-PASS full load + verify loop ----
        if (s > 0) {
            const u64* Hrd = Hd + ((size_t)((s & 1) * 2 + dir)) * (32 * 256);
            const u32 tgt = (u32)((layer << 10) | s);
            u64 v[32];
            for (;;) {
                #pragma unroll
                for (int i = 0; i < 32; ++i)
                    v[i] = __hip_atomic_load(Hrd + i * 256 + t, __ATOMIC_RELAXED,
                                             __HIP_MEMORY_SCOPE_AGENT);
                bool ok = true;
                #pragma unroll
                for (int i = 0; i < 32; ++i) {
                    ok = ok && (((u32)v[i] & 0xffffu) == tgt);
                    ok = ok && ((((u32)(v[i] >> 32)) & 0xffffu) == tgt);
                }
                if (__all(ok)) break;
            }
            // stage: row i, bf16 pair (k=2t, 2t+1) -> 4B LDS write (2-way banks)
            #pragma unroll
            for (int i = 0; i < 32; ++i) {
                u32 two = ((u32)(v[i] >> 16) & 0xffffu) | (((u32)(v[i] >> 48)) << 16);
                int off = i * 1024 + ((sc_c ^ (i & 7)) << 4) + sc_sub;
                *(u32*)((char*)hl + off) = two;
            }
        } else {
            #pragma unroll
            for (int i = 0; i < 32; ++i) {
                int off = i * 1024 + ((sc_c ^ (i & 7)) << 4) + sc_sub;
                *(u32*)((char*)hl + off) = 0u;
            }
        }
        __syncthreads();   // (1) hl + xq ready

        // ---- C: MFMA, wave g covers gate g, full K=512 (validated r3) ----
        {
            f32x4 acc0 = {0.f, 0.f, 0.f, 0.f}, acc1 = {0.f, 0.f, 0.f, 0.f};
            const int b0 = lane & 15, q = lane >> 4;
            #pragma unroll
            for (int kt = 0; kt < 16; ++kt) {
                int pc = ((kt << 2) + q) ^ (b0 & 7);
                bf16x8 a0 = *(const bf16x8*)&hl[b0 * 512 + pc * 8];
                bf16x8 a1 = *(const bf16x8*)&hl[(b0 + 16) * 512 + pc * 8];
                bf16x8 Bv = *(const bf16x8*)&Wfr[((g * 16 + kt) * 64 + lane) * 8];
                acc0 = __builtin_amdgcn_mfma_f32_16x16x32_bf16(a0, Bv, acc0, 0, 0, 0);
                acc1 = __builtin_amdgcn_mfma_f32_16x16x32_bf16(a1, Bv, acc1, 0, 0, 0);
            }
            // plane [g][batch][jj], batch-stride 18: row = q*4+r (+16), col = jj
            #pragma unroll
            for (int r = 0; r < 4; ++r) {
                gates[g * 576 + (q * 4 + r) * 18 + b0]      = acc0[r];
                gates[g * 576 + (16 + q * 4 + r) * 18 + b0] = acc1[r];
            }
        }
        __syncthreads();   // (2) gates ready

        // ---- D: elementwise epilogue (t<128): (eb, cols j0+ej*4..+3) ----
        if (t < 128) {
            float hv4[4], cv4[4];
            #pragma unroll
            for (int k = 0; k < 4; ++k) {
                int jj = ej * 4 + k;
                float gi = xq[eb * 65 +      jj] + gates[0 * 576 + eb * 18 + jj];
                float gf = xq[eb * 65 + 16 + jj] + gates[1 * 576 + eb * 18 + jj];
                float gg = xq[eb * 65 + 32 + jj] + gates[2 * 576 + eb * 18 + jj];
                float go = xq[eb * 65 + 48 + jj] + gates[3 * 576 + eb * 18 + jj];
                float ig = 1.f / (1.f + __expf(-gi));
                float fg = 1.f / (1.f + __expf(-gf));
                float gt = tanhf(gg);
                float og = 1.f / (1.f + __expf(-go));
                float c  = fg * creg[k] + ig * gt;
                float h  = og * tanhf(c);
                creg[k] = c; cv4[k] = c; hv4[k] = h;
            }
            // publish stamped h words FIRST (critical path), parity ping-pong
            u64* Hwr = Hd + ((size_t)(((s + 1) & 1) * 2 + dir)) * (32 * 256);
            const u32 pst = (u32)((layer << 10) | (s + 1));
            u32 w0 = ((u32)f2b(hv4[0]) << 16) | pst;
            u32 w1 = ((u32)f2b(hv4[1]) << 16) | pst;
            u32 w2 = ((u32)f2b(hv4[2]) << 16) | pst;
            u32 w3 = ((u32)f2b(hv4[3]) << 16) | pst;
            u64* dst = Hwr + eb * 256 + ((j0 + ej * 4) >> 1);
            __hip_atomic_store(dst,     (u64)w0 | ((u64)w1 << 32),
                               __ATOMIC_RELAXED, __HIP_MEMORY_SCOPE_AGENT);
            __hip_atomic_store(dst + 1, (u64)w2 | ((u64)w3 << 32),
                               __ATOMIC_RELAXED, __HIP_MEMORY_SCOPE_AGENT);

            union { u64 q; u16 a[4]; } ho;
            #pragma unroll
            for (int k = 0; k < 4; ++k) ho.a[k] = f2b(hv4[k]);
            if (layer == 0) {
                *(u64*)(hs0 + (size_t)sa * (BB * 1024) + (size_t)eb * 1024
                        + dir * 512 + j0 + ej * 4) = ho.q;
            } else {
                *(float4*)(out + (size_t)eb * (SS * 1024) + (size_t)sa * 1024
                           + dir * 512 + j0 + ej * 4) =
                    make_float4(hv4[0], hv4[1], hv4[2], hv4[3]);
            }
            if (s == SS - 1) {
                int sl = layer * 2 + dir;
                *(float4*)(fin + (size_t)sl * (32 * 512) + eb * 512 + j0 + ej * 4) =
                    make_float4(hv4[0], hv4[1], hv4[2], hv4[3]);
                *(float4*)(fin + 65536 + (size_t)sl * (32 * 512) + eb * 512 + j0 + ej * 4) =
                    make_float4(cv4[0], cv4[1], cv4[2], cv4[3]);
            }
        }
        __syncthreads();   // (3) xq/gates free for next step
    }
}

// ---------------- workspace layout (bytes) ----------------
#define OFF_XBF   ((size_t)0)                       // 16,777,216
#define OFF_HS0   ((size_t)16777216)                // 33,554,432
#define OFF_XPF   ((size_t)50331648)                // 67,108,864
#define OFF_XPB   ((size_t)117440512)               // 67,108,864
#define OFF_WIH0F ((size_t)184549376)               // 2,097,152
#define OFF_WIH0B ((size_t)186646528)               // 2,097,152
#define OFF_WIH1F ((size_t)188743680)               // 4,194,304
#define OFF_WIH1B ((size_t)192937984)               // 4,194,304
#define OFF_HST   ((size_t)197132288)               // 262,144 (stamped h)

extern "C" void kernel_launch(void* const* d_in, const int* in_sizes, int n_in,
                              void* d_out, int out_size, void* d_ws, size_t ws_size,
                              hipStream_t stream) {
    const float* x      = (const float*)d_in[0];
    const float* wih0f  = (const float*)d_in[1];
    const float* whh0f  = (const float*)d_in[2];
    const float* bih0f  = (const float*)d_in[3];
    const float* bhh0f  = (const float*)d_in[4];
    const float* wih0b  = (const float*)d_in[5];
    const float* whh0b  = (const float*)d_in[6];
    const float* bih0b  = (const float*)d_in[7];
    const float* bhh0b  = (const float*)d_in[8];
    const float* wih1f  = (const float*)d_in[9];
    const float* whh1f  = (const float*)d_in[10];
    const float* bih1f  = (const float*)d_in[11];
    const float* bhh1f  = (const float*)d_in[12];
    const float* wih1b  = (const float*)d_in[13];
    const float* whh1b  = (const float*)d_in[14];
    const float* bih1b  = (const float*)d_in[15];
    const float* bhh1b  = (const float*)d_in[16];

    float* out = (float*)d_out;
    char* ws = (char*)d_ws;

    u16* xbf    = (u16*)(ws + OFF_XBF);
    u16* hs0    = (u16*)(ws + OFF_HS0);
    u16* xpf    = (u16*)(ws + OFF_XPF);
    u16* xpb    = (u16*)(ws + OFF_XPB);
    u16* bwih0f = (u16*)(ws + OFF_WIH0F);
    u16* bwih0b = (u16*)(ws + OFF_WIH0B);
    u16* bwih1f = (u16*)(ws + OFF_WIH1F);
    u16* bwih1b = (u16*)(ws + OFF_WIH1B);
    u64* Hd     = (u64*)(ws + OFF_HST);
    float* fin  = out + 16777216;   // final h stack, then c stack at +65536

    // converts
    k_convert_x<<<1024, 256, 0, stream>>>(x, xbf);
    k_cast<<<512, 256, 0, stream>>>(wih0f, bwih0f, 2048 * 512 / 4);
    k_cast<<<512, 256, 0, stream>>>(wih0b, bwih0b, 2048 * 512 / 4);
    k_cast<<<512, 256, 0, stream>>>(wih1f, bwih1f, 2048 * 1024 / 4);
    k_cast<<<512, 256, 0, stream>>>(wih1b, bwih1b, 2048 * 1024 / 4);

    // zero stamped-h buffer once (first-call garbage; stale stamps are
    // layer-tagged; leftover same-layer stamps from a previous replay carry
    // identical deterministic values, so a match is harmless)
    hipMemsetAsync(ws + OFF_HST, 0, 262144, stream);

    // layer 0
    k_proj<<<dim3(128, 16, 2), 256, 0, stream>>>(
        xbf, bwih0f, bwih0b, bih0f, bhh0f, bih0b, bhh0b, xpf, xpb, 512);
    k_rec<<<64, 256, 0, stream>>>(xpf, xpb, whh0f, whh0b, Hd,
                                  hs0, nullptr, fin, 0);

    // layer 1
    k_proj<<<dim3(128, 16, 2), 256, 0, stream>>>(
        hs0, bwih1f, bwih1b, bih1f, bhh1f, bih1b, bhh1b, xpf, xpb, 1024);
    k_rec<<<64, 256, 0, stream>>>(xpf, xpb, whh1f, whh1b, Hd,
                                  nullptr, out, fin, 1);
}